// Round 1
// baseline (472.811 us; speedup 1.0000x reference)
//
#include <hip/hip_runtime.h>

#define H    128
#define WP   130
#define NCH  256
#define NB   24

// Face order: back(0), down(1), front(2), left(3), right(4), top(5)
__constant__ int c_R[6][9] = {
  {-1,0,0,  0,1,0,  0,0,-1},   // back  = Ry(pi)
  { 1,0,0,  0,0,-1, 0,1,0 },   // down  = Rx(pi/2)
  { 1,0,0,  0,1,0,  0,0,1 },   // front = I
  { 0,0,1,  0,1,0, -1,0,0 },   // left  = Ry(pi/2)
  { 0,0,-1, 0,1,0,  1,0,0 },   // right = Ry(-pi/2)
  { 1,0,0,  0,0,1,  0,-1,0},   // top   = Rx(-pi/2)
};

// NEIGHBORS[face][side], side order: up(0), down(1), left(2), right(3)
__constant__ int c_conn[6][4] = {
  {5,1,4,3}, // back : top,down,right,left
  {2,0,3,4}, // down : front,back,left,right
  {5,1,3,4}, // front: top,down,left,right
  {5,1,0,2}, // left : top,down,back,front
  {5,1,2,0}, // right: top,down,front,back
  {0,2,3,4}, // top  : back,front,left,right
};

// u(i) = (i - 64.5) / fp,  fp = 64.5*64/65  ->  u(i) = (i-64.5)*65/4128
#define INV_FP (65.0f / 4128.0f)

__global__ void __launch_bounds__(256)
spherepad_kernel(const float* __restrict__ in, float* __restrict__ out) {
  unsigned tid = blockIdx.x * 256u + threadIdx.x;
  const unsigned total = (unsigned)NB * NCH * WP * WP;
  if (tid >= total) return;

  unsigned img = tid / (WP * WP);          // n*256 + ch, 0..6143
  unsigned pix = tid - img * (WP * WP);
  int r = (int)(pix / WP);
  int c = (int)(pix - (unsigned)r * WP);

  float v;
  if ((unsigned)(r - 1) < (unsigned)H && (unsigned)(c - 1) < (unsigned)H) {
    // interior: plain shifted copy
    v = in[((unsigned)img * H + (unsigned)(r - 1)) * H + (unsigned)(c - 1)];
  } else {
    int n    = (int)(img / NCH);
    int ch   = (int)(img - (unsigned)n * NCH);
    int face = n % 6;
    int rep  = n / 6;
    v = 0.0f;

    // candidate sides, highest priority first (right > left > down > up)
    int cand[2]; int nc = 0;
    if (c == WP - 1) cand[nc++] = 3;
    if (c == 0)      cand[nc++] = 2;
    if (r == WP - 1) cand[nc++] = 1;
    if (r == 0)      cand[nc++] = 0;

    float uc = ((float)c - 64.5f) * INV_FP;
    float ur = ((float)r - 64.5f) * INV_FP;

    for (int k = 0; k < nc; ++k) {
      int s  = cand[k];
      int cf = c_conn[face][s];
      const int* Rc = c_R[cf];
      const int* Rf = c_R[face];
      // g = Rrel * d, Rrel = R[cf] * R[face]^T, d = (uc, ur, 1)
      float g[3];
      #pragma unroll
      for (int i = 0; i < 3; ++i) {
        float acc = 0.0f;
        #pragma unroll
        for (int j = 0; j < 3; ++j) {
          int rr = Rc[i*3+0]*Rf[j*3+0] + Rc[i*3+1]*Rf[j*3+1] + Rc[i*3+2]*Rf[j*3+2];
          float dj = (j == 0) ? uc : (j == 1) ? ur : 1.0f;
          acc += (float)rr * dj;
        }
        g[i] = acc;
      }
      float x = g[0] / g[2];
      float y = g[1] / g[2];
      if (fabsf(x) <= 1.01f && fabsf(y) <= 1.01f) {
        x = fminf(fmaxf(x, -1.0f), 1.0f);
        y = fminf(fmaxf(y, -1.0f), 1.0f);
        const float* src = in + ((size_t)((rep * 6 + cf) * NCH + ch)) * H * H;
        float xp = (x + 1.0f) * 0.5f * (float)(H - 1);
        float yp = (y + 1.0f) * 0.5f * (float)(H - 1);
        float x0 = floorf(xp), y0 = floorf(yp);
        float wx = xp - x0,    wy = yp - y0;
        int x0i = min(max((int)x0, 0), H - 1);
        int x1i = min(x0i + 1, H - 1);
        int y0i = min(max((int)y0, 0), H - 1);
        int y1i = min(y0i + 1, H - 1);
        float v00 = src[y0i * H + x0i];
        float v01 = src[y0i * H + x1i];
        float v10 = src[y1i * H + x0i];
        float v11 = src[y1i * H + x1i];
        v = v00 * (1.0f - wx) * (1.0f - wy)
          + v01 * wx          * (1.0f - wy)
          + v10 * (1.0f - wx) * wy
          + v11 * wx          * wy;
        break;
      }
    }
  }
  out[tid] = v;
}

extern "C" void kernel_launch(void* const* d_in, const int* in_sizes, int n_in,
                              void* d_out, int out_size, void* d_ws, size_t ws_size,
                              hipStream_t stream) {
  (void)in_sizes; (void)n_in; (void)d_ws; (void)ws_size; (void)out_size;
  const float* in = (const float*)d_in[0];
  float* out = (float*)d_out;
  const unsigned total = (unsigned)NB * NCH * WP * WP;   // 103,833,600
  const unsigned blocks = (total + 255u) / 256u;
  spherepad_kernel<<<blocks, 256, 0, stream>>>(in, out);
}

// Round 2
// 270.924 us; speedup vs baseline: 1.7452x; 1.7452x over previous
//
#include <hip/hip_runtime.h>

#define H    128
#define WP   130
#define NCH  256
#define NB   24

// Face order: back(0), down(1), front(2), left(3), right(4), top(5)
__constant__ int c_R[6][9] = {
  {-1,0,0,  0,1,0,  0,0,-1},   // back  = Ry(pi)
  { 1,0,0,  0,0,-1, 0,1,0 },   // down  = Rx(pi/2)
  { 1,0,0,  0,1,0,  0,0,1 },   // front = I
  { 0,0,1,  0,1,0, -1,0,0 },   // left  = Ry(pi/2)
  { 0,0,-1, 0,1,0,  1,0,0 },   // right = Ry(-pi/2)
  { 1,0,0,  0,0,1,  0,-1,0},   // top   = Rx(-pi/2)
};

// NEIGHBORS[face][side], side order: up(0), down(1), left(2), right(3)
__constant__ int c_conn[6][4] = {
  {5,1,4,3}, // back
  {2,0,3,4}, // down
  {5,1,3,4}, // front
  {5,1,0,2}, // left
  {5,1,2,0}, // right
  {0,2,3,4}, // top
};

#define INV_FP (65.0f / 4128.0f)

// ---------------- interior: pure vectorized copy -------------------------
// One thread per input float4. 6144 imgs * 128 rows * 32 float4 = 25,165,824
// threads = 98304 blocks * 256. Index math is shifts/masks only.
__global__ void __launch_bounds__(256)
interior_kernel(const float4* __restrict__ in4, float* __restrict__ out) {
  unsigned t = blockIdx.x * 256u + threadIdx.x;
  unsigned c4  = t & 31u;          // float4 index within row (0..31)
  unsigned r   = (t >> 5) & 127u;  // input row (0..127)
  unsigned img = t >> 12;          // n*256+ch (0..6143)
  float4 v = in4[t];               // input is contiguous: float4 idx == t
  unsigned o = img * 16900u + (r + 1u) * 130u + 1u + (c4 << 2);
  out[o]     = v.x;
  out[o + 1] = v.y;
  out[o + 2] = v.z;
  out[o + 3] = v.w;
}

// ---------------- border ring --------------------------------------------
// 516 border pixels per image (r=0 row, r=129 row, c=0 col, c=129 col).
// 6144 * 516 = 3,170,304 threads.
__global__ void __launch_bounds__(256)
border_kernel(const float* __restrict__ in, float* __restrict__ out) {
  unsigned tid = blockIdx.x * 256u + threadIdx.x;
  const unsigned total = 6144u * 516u;
  if (tid >= total) return;

  unsigned img = tid / 516u;
  unsigned k   = tid - img * 516u;

  int r, c;
  if (k < 130u)      { r = 0;              c = (int)k; }
  else if (k < 260u) { r = WP - 1;         c = (int)(k - 130u); }
  else if (k < 388u) { r = (int)(k - 259u); c = 0; }          // r in 1..128
  else               { r = (int)(k - 387u); c = WP - 1; }     // r in 1..128

  int n    = (int)(img >> 8);        // NCH = 256
  int ch   = (int)(img & 255u);
  int face = n % 6;
  int rep  = n / 6;
  float v  = 0.0f;

  // candidate sides, highest priority first (right > left > down > up)
  int cand[2]; int nc = 0;
  if (c == WP - 1) cand[nc++] = 3;
  if (c == 0)      cand[nc++] = 2;
  if (r == WP - 1) cand[nc++] = 1;
  if (r == 0)      cand[nc++] = 0;

  float uc = ((float)c - 64.5f) * INV_FP;
  float ur = ((float)r - 64.5f) * INV_FP;

  for (int kk = 0; kk < nc; ++kk) {
    int s  = cand[kk];
    int cf = c_conn[face][s];
    const int* Rc = c_R[cf];
    const int* Rf = c_R[face];
    float g[3];
    #pragma unroll
    for (int i = 0; i < 3; ++i) {
      float acc = 0.0f;
      #pragma unroll
      for (int j = 0; j < 3; ++j) {
        int rr = Rc[i*3+0]*Rf[j*3+0] + Rc[i*3+1]*Rf[j*3+1] + Rc[i*3+2]*Rf[j*3+2];
        float dj = (j == 0) ? uc : (j == 1) ? ur : 1.0f;
        acc += (float)rr * dj;
      }
      g[i] = acc;
    }
    float x = g[0] / g[2];
    float y = g[1] / g[2];
    if (fabsf(x) <= 1.01f && fabsf(y) <= 1.01f) {
      x = fminf(fmaxf(x, -1.0f), 1.0f);
      y = fminf(fmaxf(y, -1.0f), 1.0f);
      const float* src = in + ((size_t)((rep * 6 + cf) * NCH + ch)) * H * H;
      float xp = (x + 1.0f) * 0.5f * (float)(H - 1);
      float yp = (y + 1.0f) * 0.5f * (float)(H - 1);
      float x0 = floorf(xp), y0 = floorf(yp);
      float wx = xp - x0,    wy = yp - y0;
      int x0i = min(max((int)x0, 0), H - 1);
      int x1i = min(x0i + 1, H - 1);
      int y0i = min(max((int)y0, 0), H - 1);
      int y1i = min(y0i + 1, H - 1);
      float v00 = src[y0i * H + x0i];
      float v01 = src[y0i * H + x1i];
      float v10 = src[y1i * H + x0i];
      float v11 = src[y1i * H + x1i];
      v = v00 * (1.0f - wx) * (1.0f - wy)
        + v01 * wx          * (1.0f - wy)
        + v10 * (1.0f - wx) * wy
        + v11 * wx          * wy;
      break;
    }
  }
  out[(unsigned)img * 16900u + (unsigned)r * 130u + (unsigned)c] = v;
}

extern "C" void kernel_launch(void* const* d_in, const int* in_sizes, int n_in,
                              void* d_out, int out_size, void* d_ws, size_t ws_size,
                              hipStream_t stream) {
  (void)in_sizes; (void)n_in; (void)d_ws; (void)ws_size; (void)out_size;
  const float* in = (const float*)d_in[0];
  float* out = (float*)d_out;

  // interior: 25,165,824 threads exactly
  interior_kernel<<<98304, 256, 0, stream>>>((const float4*)in, out);

  // border: 3,170,304 threads
  const unsigned btotal  = 6144u * 516u;
  const unsigned bblocks = (btotal + 255u) / 256u;
  border_kernel<<<bblocks, 256, 0, stream>>>(in, out);
}